// Round 14
// baseline (314.429 us; speedup 1.0000x reference)
//
#include <hip/hip_runtime.h>
#include <hip/hip_fp16.h>
#include <math.h>

// ChebConv (K=4) GNN head. N=50000, E=800000, F_IN=64, H=128.
// R14 = R12 (NT hints of R13 reverted) + degree-bucketed row ordering:
// SPMM waves process 8 equal-length rows (Poisson tail divergence was ~40%
// of issue slots). rowlist built via 32-bin counting sort (3 small kernels).

#define FIN 64
#define HDIM 128

typedef _Float16 half8 __attribute__((ext_vector_type(8)));
typedef float f32x4 __attribute__((ext_vector_type(4)));

union U16 { uint4 u; __half2 h2[4]; half8 h8; };

// count_deg + cvt_feat + make_bfrag fused (independent; grid sized for E).
__global__ void fused_pre(const int* __restrict__ row, int* __restrict__ deg, int E,
                          const float4* __restrict__ fsrc, uint4* __restrict__ fdst, int n8,
                          const float* __restrict__ W, uint4* __restrict__ bfrag) {
    int i = blockIdx.x * blockDim.x + threadIdx.x;
    if (i < E) atomicAdd(&deg[row[i]], 1);
    if (i < n8) {
        float4 a = fsrc[i * 2], b = fsrc[i * 2 + 1];
        U16 v;
        v.h2[0] = __float22half2_rn(make_float2(a.x, a.y));
        v.h2[1] = __float22half2_rn(make_float2(a.z, a.w));
        v.h2[2] = __float22half2_rn(make_float2(b.x, b.y));
        v.h2[3] = __float22half2_rn(make_float2(b.z, b.w));
        fdst[i] = v.u;
    }
    if (i < 8 * 8 * 64) {
        int lane = i & 63;
        int ht = (i >> 6) & 7;
        int kk = i >> 9;
        int h = ht * 16 + (lane & 15);
        int kb = kk * 32 + (lane >> 4) * 8;
        U16 v;
#pragma unroll
        for (int j = 0; j < 4; ++j) {
            float a = W[(kb + 2 * j) * HDIM + h];
            float b = W[(kb + 2 * j + 1) * HDIM + h];
            v.h2[j] = __float22half2_rn(make_float2(a, b));
        }
        bfrag[i] = v.u;
    }
}

__device__ inline int deg_bin(int pd) { return min(pd >> 2, 31); }

// Row-span allocation (wave shfl-scan + one atomicAdd/wave) + dinv + permuted
// cursors + wave-aggregated degree-bin histogram.
__global__ void alloc_rows(const int* __restrict__ deg, float* __restrict__ dinv,
                           int2* __restrict__ rowspan, int* __restrict__ cursor,
                           int* __restrict__ ctr, int* __restrict__ binCount,
                           int n, int stride8) {
    int i = blockIdx.x * blockDim.x + threadIdx.x;
    int lane = threadIdx.x & 63;
    int d = (i < n) ? deg[i] : 0;
    if (i < n) dinv[i] = (d > 0) ? rsqrtf((float)d) : 0.f;
    int pd = (i < n) ? ((d + 3) & ~3) : 0;
    int x = pd;                        // inclusive wave scan
    for (int off = 1; off < 64; off <<= 1) {
        int t = __shfl_up(x, off, 64);
        if (lane >= off) x += t;
    }
    int excl = x - pd;
    int total = __shfl(x, 63, 64);
    int base = 0;
    if (lane == 0 && total > 0) base = atomicAdd(ctr, total);
    base = __shfl(base, 0, 64);
    if (i < n) {
        int b = base + excl;
        rowspan[i] = make_int2(b, b + pd);
        cursor[(i & 7) * stride8 + (i >> 3)] = b;
    }
    // wave-aggregated histogram over 32 degree bins
    int mybin = (i < n) ? deg_bin(pd) : -1;
    for (int b = 0; b < 32; ++b) {
        unsigned long long mask = __ballot(mybin == b);
        if (mask && lane == (__ffsll((long long)mask) - 1))
            atomicAdd(&binCount[b], __popcll(mask));
    }
}

// One wave: exclusive scan of 32 bin counts -> binCursor.
__global__ void bin_scan(const int* __restrict__ binCount, int* __restrict__ binCursor) {
    int lane = threadIdx.x;
    int c = (lane < 32) ? binCount[lane] : 0;
    int x = c;
    for (int off = 1; off < 64; off <<= 1) {
        int t = __shfl_up(x, off, 64);
        if (lane >= off) x += t;
    }
    if (lane < 32) binCursor[lane] = x - c;
}

// Emit rowlist grouped by degree bin (wave-aggregated cursor bumps).
__global__ void sort_rows(const int* __restrict__ deg, int* __restrict__ binCursor,
                          int* __restrict__ rowlist, int n) {
    int i = blockIdx.x * blockDim.x + threadIdx.x;
    int lane = threadIdx.x & 63;
    int pd = (i < n) ? ((deg[i] + 3) & ~3) : 0;
    int mybin = (i < n) ? deg_bin(pd) : -1;
    for (int b = 0; b < 32; ++b) {
        unsigned long long mask = __ballot(mybin == b);
        if (mybin == b) {
            int leader = __ffsll((long long)mask) - 1;
            int base = 0;
            if (lane == leader) base = atomicAdd(&binCursor[b], __popcll(mask));
            base = __shfl(base, leader, 64);
            int posin = __popcll(mask & ((1ull << lane) - 1ull));
            rowlist[base + posin] = i;
        }
    }
}

// XCD-owned scatter: grid = 8 * ceil(E/256); xcd = blockIdx&7 (round-robin
// heuristic). Every epk line + cursor written by ONE XCD.
__global__ void scatter_xcd(const int* __restrict__ row, const int* __restrict__ col,
                            const float* __restrict__ dinv, int* __restrict__ cursor,
                            int2* __restrict__ epk, int E, int stride8) {
    int xcd = blockIdx.x & 7;
    int e = (blockIdx.x >> 3) * blockDim.x + threadIdx.x;
    if (e < E) {
        int r = row[e];
        if ((r & 7) == xcd) {
            int c = col[e];
            int p = atomicAdd(&cursor[xcd * stride8 + (r >> 3)], 1);
            float w = -dinv[r] * dinv[c];   // L_hat = -D^-1/2 A D^-1/2
            epk[p] = make_int2(c, __float_as_int(w));
        }
    }
}

// 8 rows/wave (equal-length via rowlist), 8 lanes/row, 16B per lane, fp32
// accumulate. Padded spans ((e-s)%4==0, pads (col=0,w=0)); 2-deep pipeline.
__global__ __launch_bounds__(256) void spmm_h(
        const int* __restrict__ rowlist, const int2* __restrict__ rowspan,
        const int2* __restrict__ epk, const uint4* __restrict__ in8,
        const uint4* __restrict__ prev8, float scale,
        uint4* __restrict__ out8, int n) {
    int lane = threadIdx.x & 63;
    int wid = (blockIdx.x * blockDim.x + threadIdx.x) >> 6;
    int li = lane & 7, g = lane >> 3;
    int idx = wid * 8 + g;
    if (idx >= n) return;
    int r = rowlist[idx];
    int2 span = rowspan[r];
    int s = span.x, e = span.y;

    U16 pv;
    if (prev8) pv.u = prev8[(size_t)r * 8 + li];   // in flight across the loop

    float acc[8];
#pragma unroll
    for (int j = 0; j < 8; ++j) acc[j] = 0.f;

    if (s < e) {
        int2 mc[4], mn[4];
        U16 vc[4];
#pragma unroll
        for (int j = 0; j < 4; ++j) mc[j] = epk[s + j];
#pragma unroll
        for (int j = 0; j < 4; ++j) vc[j].u = in8[(size_t)mc[j].x * 8 + li];
        if (s + 4 < e) {
#pragma unroll
            for (int j = 0; j < 4; ++j) mn[j] = epk[s + 4 + j];
        }
        for (int p = s;;) {
            bool more = p + 4 < e;
            bool more2 = p + 8 < e;
            U16 vn[4];
            int2 m2[4];
            if (more) {
#pragma unroll
                for (int j = 0; j < 4; ++j) vn[j].u = in8[(size_t)mn[j].x * 8 + li];
            }
            if (more2) {
#pragma unroll
                for (int j = 0; j < 4; ++j) m2[j] = epk[p + 8 + j];
            }
            float w0 = __int_as_float(mc[0].y), w1 = __int_as_float(mc[1].y);
            float w2 = __int_as_float(mc[2].y), w3 = __int_as_float(mc[3].y);
#pragma unroll
            for (int j = 0; j < 4; ++j) {
                float2 f0 = __half22float2(vc[0].h2[j]);
                float2 f1 = __half22float2(vc[1].h2[j]);
                float2 f2 = __half22float2(vc[2].h2[j]);
                float2 f3 = __half22float2(vc[3].h2[j]);
                acc[2 * j]     = fmaf(w0, f0.x, acc[2 * j]);
                acc[2 * j + 1] = fmaf(w0, f0.y, acc[2 * j + 1]);
                acc[2 * j]     = fmaf(w1, f1.x, acc[2 * j]);
                acc[2 * j + 1] = fmaf(w1, f1.y, acc[2 * j + 1]);
                acc[2 * j]     = fmaf(w2, f2.x, acc[2 * j]);
                acc[2 * j + 1] = fmaf(w2, f2.y, acc[2 * j + 1]);
                acc[2 * j]     = fmaf(w3, f3.x, acc[2 * j]);
                acc[2 * j + 1] = fmaf(w3, f3.y, acc[2 * j + 1]);
            }
            if (!more) break;
#pragma unroll
            for (int j = 0; j < 4; ++j) {
                mc[j] = mn[j];
                mn[j] = m2[j];   // garbage when !more2; never gathered then
                vc[j] = vn[j];
            }
            p += 4;
        }
    }

    float res[8];
    if (prev8) {
#pragma unroll
        for (int t = 0; t < 4; ++t) {
            float2 f = __half22float2(pv.h2[t]);
            res[2 * t]     = fmaf(scale, acc[2 * t], -f.x);
            res[2 * t + 1] = fmaf(scale, acc[2 * t + 1], -f.y);
        }
    } else {
#pragma unroll
        for (int j = 0; j < 8; ++j) res[j] = scale * acc[j];
    }
    U16 ru;
#pragma unroll
    for (int t = 0; t < 4; ++t)
        ru.h2[t] = __float22half2_rn(make_float2(res[2 * t], res[2 * t + 1]));
    out8[(size_t)r * 8 + li] = ru.u;
}

__device__ inline float tanh_fast(float x) {
    x = fmaxf(-10.f, fminf(10.f, x));
    float e = __expf(2.f * x);
    return (e - 1.f) / (e + 1.f);
}

// MFMA GEMM + tanh + final dot. Block = 256 thr = 4 waves; wave = 16 nodes x
// 128 h (8 tiles of 16x16, K=32/step, 8 steps over K=256). LDS-free.
__global__ __launch_bounds__(256) void gemm_mfma(
        const uint4* __restrict__ tx0, const uint4* __restrict__ tx1,
        const uint4* __restrict__ tx2, const uint4* __restrict__ tx3,
        const uint4* __restrict__ bfrag,
        const float* __restrict__ cheb_b, const float* __restrict__ fw,
        const float* __restrict__ fb, float* __restrict__ out, int n) {
    int tid = threadIdx.x;
    int lane = tid & 63;
    int wave = tid >> 6;
    int q = lane >> 4, m = lane & 15;
    int node_base = blockIdx.x * 64 + wave * 16;
    int node = node_base + m;
    size_t nd = (node < n) ? (size_t)node : 0;   // clamp; store is guarded

    f32x4 acc[8];
#pragma unroll
    for (int t = 0; t < 8; ++t) acc[t] = (f32x4){0.f, 0.f, 0.f, 0.f};

    const uint4* txs[4] = {tx0, tx1, tx2, tx3};
#pragma unroll
    for (int kk = 0; kk < 8; ++kk) {
        U16 av;
        av.u = txs[kk >> 1][nd * 8 + (kk & 1) * 4 + q];
#pragma unroll
        for (int ht = 0; ht < 8; ++ht) {
            U16 bv;
            bv.u = bfrag[(kk * 8 + ht) * 64 + lane];
            acc[ht] = __builtin_amdgcn_mfma_f32_16x16x32_f16(av.h8, bv.h8, acc[ht], 0, 0, 0);
        }
    }

    float s[4] = {0.f, 0.f, 0.f, 0.f};
#pragma unroll
    for (int ht = 0; ht < 8; ++ht) {
        int h = ht * 16 + m;
        float cb = cheb_b[h];
        float fv = fw[h];
#pragma unroll
        for (int r = 0; r < 4; ++r)
            s[r] = fmaf(tanh_fast(acc[ht][r] + cb), fv, s[r]);
    }
#pragma unroll
    for (int r = 0; r < 4; ++r) {
        for (int msk = 1; msk < 16; msk <<= 1)
            s[r] += __shfl_xor(s[r], msk, 64);
    }
    if (m == 0) {
        float fb0 = fb[0];
#pragma unroll
        for (int r = 0; r < 4; ++r) {
            int o = node_base + q * 4 + r;
            if (o < n) out[o] = s[r] + fb0;
        }
    }
}

extern "C" void kernel_launch(void* const* d_in, const int* in_sizes, int n_in,
                              void* d_out, int out_size, void* d_ws, size_t ws_size,
                              hipStream_t stream) {
    const float* features = (const float*)d_in[0];
    const int*   edge_index = (const int*)d_in[1];
    const float* cheb_w  = (const float*)d_in[2];
    const float* cheb_b  = (const float*)d_in[3];
    const float* final_w = (const float*)d_in[4];
    const float* final_b = (const float*)d_in[5];
    int N = in_sizes[0] / FIN;
    int E = in_sizes[1] / 2;
    const int* row = edge_index;        // edge_index[0, :]
    const int* col = edge_index + E;    // edge_index[1, :]
    int E_pad = E + 4 * N;              // allocation bound on padded edges
    int stride8 = (N + 7) / 8;

    char* p = (char*)d_ws;
    auto alloc = [&](size_t bytes) {
        char* r = p;
        p += (bytes + 255) & ~(size_t)255;
        return r;
    };
    // ctr + binCount + deg + epk adjacent: ONE memset zeroes all
    // (epk pad slots = col 0, w 0).
    int*   ctr     = (int*)alloc(256);
    int*   binCount= (int*)alloc(32 * 4);
    int*   deg     = (int*)alloc((size_t)N * 4);
    int2*  epk     = (int2*)alloc((size_t)E_pad * 8);
    size_t zero_bytes = (char*)(epk + E_pad) - (char*)ctr;
    float* dinv    = (float*)alloc((size_t)N * 4);
    int2*  rowspan = (int2*)alloc((size_t)N * 8);
    int*   cursor  = (int*)alloc((size_t)(stride8 * 8) * 4);
    int*   binCursor = (int*)alloc(32 * 4);
    int*   rowlist = (int*)alloc((size_t)N * 4);
    uint4* feath   = (uint4*)alloc((size_t)N * FIN * 2);   // fp16 rows
    uint4* tx1h    = (uint4*)alloc((size_t)N * FIN * 2);
    uint4* tx2h    = (uint4*)alloc((size_t)N * FIN * 2);
    uint4* tx3h    = (uint4*)alloc((size_t)N * FIN * 2);
    uint4* bfrag   = (uint4*)alloc(4096 * 16);             // 64 KB B fragments

    hipMemsetAsync(ctr, 0, zero_bytes, stream);
    int n8 = N * FIN / 8;
    int eb = (E + 255) / 256;
    fused_pre<<<eb, 256, 0, stream>>>(row, deg, E, (const float4*)features, feath,
                                      n8, cheb_w, bfrag);
    alloc_rows<<<(N + 255) / 256, 256, 0, stream>>>(deg, dinv, rowspan, cursor,
                                                    ctr, binCount, N, stride8);
    bin_scan<<<1, 64, 0, stream>>>(binCount, binCursor);
    sort_rows<<<(N + 255) / 256, 256, 0, stream>>>(deg, binCursor, rowlist, N);
    scatter_xcd<<<eb * 8, 256, 0, stream>>>(row, col, dinv, cursor, epk, E, stride8);

    int spmm_blocks = (((N + 7) / 8) * 64 + 255) / 256;
    // Tx1 = L_hat @ x
    spmm_h<<<spmm_blocks, 256, 0, stream>>>(rowlist, rowspan, epk, feath, nullptr,
                                            1.f, tx1h, N);
    // Tx2 = 2 * L_hat @ Tx1 - Tx0
    spmm_h<<<spmm_blocks, 256, 0, stream>>>(rowlist, rowspan, epk, tx1h, feath,
                                            2.f, tx2h, N);
    // Tx3 = 2 * L_hat @ Tx2 - Tx1
    spmm_h<<<spmm_blocks, 256, 0, stream>>>(rowlist, rowspan, epk, tx2h, tx1h,
                                            2.f, tx3h, N);

    gemm_mfma<<<(N + 63) / 64, 256, 0, stream>>>(feath, tx1h, tx2h, tx3h, bfrag,
                                                 cheb_b, final_w, final_b,
                                                 (float*)d_out, N);
}

// Round 15
// 238.375 us; speedup vs baseline: 1.3191x; 1.3191x over previous
//
#include <hip/hip_runtime.h>
#include <hip/hip_fp16.h>
#include <math.h>

// ChebConv (K=4) GNN head. N=50000, E=800000, F_IN=64, H=128.
// R15 = R14's degree-bucketed SPMM with a properly-priced counting sort:
// LDS histograms (no ballot loops, no global-atomic contention), bin-major
// per-block counts, 1-block scan, LDS-cursor emission. ~12us total vs R14's
// ~100us. Rest = R12 structure.

#define FIN 64
#define HDIM 128

typedef _Float16 half8 __attribute__((ext_vector_type(8)));
typedef float f32x4 __attribute__((ext_vector_type(4)));

union U16 { uint4 u; __half2 h2[4]; half8 h8; };

__device__ inline int deg_bin(int pd) { return min(pd >> 2, 31); }

// count_deg + cvt_feat + make_bfrag fused (independent; grid sized for E).
__global__ void fused_pre(const int* __restrict__ row, int* __restrict__ deg, int E,
                          const float4* __restrict__ fsrc, uint4* __restrict__ fdst, int n8,
                          const float* __restrict__ W, uint4* __restrict__ bfrag) {
    int i = blockIdx.x * blockDim.x + threadIdx.x;
    if (i < E) atomicAdd(&deg[row[i]], 1);
    if (i < n8) {
        float4 a = fsrc[i * 2], b = fsrc[i * 2 + 1];
        U16 v;
        v.h2[0] = __float22half2_rn(make_float2(a.x, a.y));
        v.h2[1] = __float22half2_rn(make_float2(a.z, a.w));
        v.h2[2] = __float22half2_rn(make_float2(b.x, b.y));
        v.h2[3] = __float22half2_rn(make_float2(b.z, b.w));
        fdst[i] = v.u;
    }
    if (i < 8 * 8 * 64) {
        int lane = i & 63;
        int ht = (i >> 6) & 7;
        int kk = i >> 9;
        int h = ht * 16 + (lane & 15);
        int kb = kk * 32 + (lane >> 4) * 8;
        U16 v;
#pragma unroll
        for (int j = 0; j < 4; ++j) {
            float a = W[(kb + 2 * j) * HDIM + h];
            float b = W[(kb + 2 * j + 1) * HDIM + h];
            v.h2[j] = __float22half2_rn(make_float2(a, b));
        }
        bfrag[i] = v.u;
    }
}

// Row-span allocation (wave shfl-scan + one atomicAdd/wave) + dinv + permuted
// cursors + per-block LDS degree-bin histogram (bin-major blockBin output).
__global__ void alloc_rows(const int* __restrict__ deg, float* __restrict__ dinv,
                           int2* __restrict__ rowspan, int* __restrict__ cursor,
                           int* __restrict__ ctr, int* __restrict__ blockBin,
                           int nblk, int n, int stride8) {
    __shared__ int hist[32];
    int tid = threadIdx.x;
    if (tid < 32) hist[tid] = 0;
    __syncthreads();
    int i = blockIdx.x * blockDim.x + tid;
    int lane = tid & 63;
    int d = (i < n) ? deg[i] : 0;
    if (i < n) dinv[i] = (d > 0) ? rsqrtf((float)d) : 0.f;
    int pd = (i < n) ? ((d + 3) & ~3) : 0;
    int x = pd;                        // inclusive wave scan
    for (int off = 1; off < 64; off <<= 1) {
        int t = __shfl_up(x, off, 64);
        if (lane >= off) x += t;
    }
    int excl = x - pd;
    int total = __shfl(x, 63, 64);
    int base = 0;
    if (lane == 0 && total > 0) base = atomicAdd(ctr, total);
    base = __shfl(base, 0, 64);
    if (i < n) {
        int b = base + excl;
        rowspan[i] = make_int2(b, b + pd);
        cursor[(i & 7) * stride8 + (i >> 3)] = b;
        atomicAdd(&hist[deg_bin(pd)], 1);    // LDS atomic, 32 banks = 32 bins
    }
    __syncthreads();
    if (tid < 32) blockBin[tid * nblk + blockIdx.x] = hist[tid];
}

// One block (256 thr = 4 waves). Per bin: exclusive shfl-scan across block
// counts (in place); then cross-bin scan of totals -> binBase.
__global__ void bin_scan2(int* __restrict__ blockBin, int* __restrict__ binBase,
                          int nblk) {
    __shared__ int totals[32];
    int tid = threadIdx.x;
    int wave = tid >> 6, lane = tid & 63;
    for (int bb = 0; bb < 8; ++bb) {
        int b = wave * 8 + bb;
        int carry = 0;
        for (int c0 = 0; c0 < nblk; c0 += 64) {
            int k = c0 + lane;
            int v = (k < nblk) ? blockBin[b * nblk + k] : 0;
            int x = v;
            for (int off = 1; off < 64; off <<= 1) {
                int t = __shfl_up(x, off, 64);
                if (lane >= off) x += t;
            }
            if (k < nblk) blockBin[b * nblk + k] = carry + x - v;  // exclusive
            carry += __shfl(x, 63, 64);
        }
        if (lane == 0) totals[b] = carry;
    }
    __syncthreads();
    if (tid < 64) {
        int c = (tid < 32) ? totals[tid] : 0;
        int x = c;
        for (int off = 1; off < 64; off <<= 1) {
            int t = __shfl_up(x, off, 64);
            if (tid >= off) x += t;
        }
        if (tid < 32) binBase[tid] = x - c;
    }
}

// Emit rowlist grouped by degree bin: LDS cursors seeded from
// binBase + per-block exclusive counts; LDS atomics for in-block position.
__global__ void sort_rows(const int* __restrict__ deg, const int* __restrict__ blockBin,
                          const int* __restrict__ binBase, int* __restrict__ rowlist,
                          int nblk, int n) {
    __shared__ int cur[32];
    int tid = threadIdx.x;
    if (tid < 32) cur[tid] = binBase[tid] + blockBin[tid * nblk + blockIdx.x];
    __syncthreads();
    int i = blockIdx.x * blockDim.x + tid;
    if (i < n) {
        int pd = (deg[i] + 3) & ~3;
        int pos = atomicAdd(&cur[deg_bin(pd)], 1);
        rowlist[pos] = i;
    }
}

// XCD-owned scatter: grid = 8 * ceil(E/256); xcd = blockIdx&7 (round-robin
// heuristic). Every epk line + cursor written by ONE XCD.
__global__ void scatter_xcd(const int* __restrict__ row, const int* __restrict__ col,
                            const float* __restrict__ dinv, int* __restrict__ cursor,
                            int2* __restrict__ epk, int E, int stride8) {
    int xcd = blockIdx.x & 7;
    int e = (blockIdx.x >> 3) * blockDim.x + threadIdx.x;
    if (e < E) {
        int r = row[e];
        if ((r & 7) == xcd) {
            int c = col[e];
            int p = atomicAdd(&cursor[xcd * stride8 + (r >> 3)], 1);
            float w = -dinv[r] * dinv[c];   // L_hat = -D^-1/2 A D^-1/2
            epk[p] = make_int2(c, __float_as_int(w));
        }
    }
}

// 8 equal-length rows/wave (via rowlist), 8 lanes/row, 16B per lane, fp32
// accumulate. Padded spans ((e-s)%4==0, pads (col=0,w=0)); 2-deep pipeline.
__global__ __launch_bounds__(256) void spmm_h(
        const int* __restrict__ rowlist, const int2* __restrict__ rowspan,
        const int2* __restrict__ epk, const uint4* __restrict__ in8,
        const uint4* __restrict__ prev8, float scale,
        uint4* __restrict__ out8, int n) {
    int lane = threadIdx.x & 63;
    int wid = (blockIdx.x * blockDim.x + threadIdx.x) >> 6;
    int li = lane & 7, g = lane >> 3;
    int idx = wid * 8 + g;
    if (idx >= n) return;
    int r = rowlist[idx];
    int2 span = rowspan[r];
    int s = span.x, e = span.y;

    U16 pv;
    if (prev8) pv.u = prev8[(size_t)r * 8 + li];   // in flight across the loop

    float acc[8];
#pragma unroll
    for (int j = 0; j < 8; ++j) acc[j] = 0.f;

    if (s < e) {
        int2 mc[4], mn[4];
        U16 vc[4];
#pragma unroll
        for (int j = 0; j < 4; ++j) mc[j] = epk[s + j];
#pragma unroll
        for (int j = 0; j < 4; ++j) vc[j].u = in8[(size_t)mc[j].x * 8 + li];
        if (s + 4 < e) {
#pragma unroll
            for (int j = 0; j < 4; ++j) mn[j] = epk[s + 4 + j];
        }
        for (int p = s;;) {
            bool more = p + 4 < e;
            bool more2 = p + 8 < e;
            U16 vn[4];
            int2 m2[4];
            if (more) {
#pragma unroll
                for (int j = 0; j < 4; ++j) vn[j].u = in8[(size_t)mn[j].x * 8 + li];
            }
            if (more2) {
#pragma unroll
                for (int j = 0; j < 4; ++j) m2[j] = epk[p + 8 + j];
            }
            float w0 = __int_as_float(mc[0].y), w1 = __int_as_float(mc[1].y);
            float w2 = __int_as_float(mc[2].y), w3 = __int_as_float(mc[3].y);
#pragma unroll
            for (int j = 0; j < 4; ++j) {
                float2 f0 = __half22float2(vc[0].h2[j]);
                float2 f1 = __half22float2(vc[1].h2[j]);
                float2 f2 = __half22float2(vc[2].h2[j]);
                float2 f3 = __half22float2(vc[3].h2[j]);
                acc[2 * j]     = fmaf(w0, f0.x, acc[2 * j]);
                acc[2 * j + 1] = fmaf(w0, f0.y, acc[2 * j + 1]);
                acc[2 * j]     = fmaf(w1, f1.x, acc[2 * j]);
                acc[2 * j + 1] = fmaf(w1, f1.y, acc[2 * j + 1]);
                acc[2 * j]     = fmaf(w2, f2.x, acc[2 * j]);
                acc[2 * j + 1] = fmaf(w2, f2.y, acc[2 * j + 1]);
                acc[2 * j]     = fmaf(w3, f3.x, acc[2 * j]);
                acc[2 * j + 1] = fmaf(w3, f3.y, acc[2 * j + 1]);
            }
            if (!more) break;
#pragma unroll
            for (int j = 0; j < 4; ++j) {
                mc[j] = mn[j];
                mn[j] = m2[j];   // garbage when !more2; never gathered then
                vc[j] = vn[j];
            }
            p += 4;
        }
    }

    float res[8];
    if (prev8) {
#pragma unroll
        for (int t = 0; t < 4; ++t) {
            float2 f = __half22float2(pv.h2[t]);
            res[2 * t]     = fmaf(scale, acc[2 * t], -f.x);
            res[2 * t + 1] = fmaf(scale, acc[2 * t + 1], -f.y);
        }
    } else {
#pragma unroll
        for (int j = 0; j < 8; ++j) res[j] = scale * acc[j];
    }
    U16 ru;
#pragma unroll
    for (int t = 0; t < 4; ++t)
        ru.h2[t] = __float22half2_rn(make_float2(res[2 * t], res[2 * t + 1]));
    out8[(size_t)r * 8 + li] = ru.u;
}

__device__ inline float tanh_fast(float x) {
    x = fmaxf(-10.f, fminf(10.f, x));
    float e = __expf(2.f * x);
    return (e - 1.f) / (e + 1.f);
}

// MFMA GEMM + tanh + final dot. Block = 256 thr = 4 waves; wave = 16 nodes x
// 128 h (8 tiles of 16x16, K=32/step, 8 steps over K=256). LDS-free.
__global__ __launch_bounds__(256) void gemm_mfma(
        const uint4* __restrict__ tx0, const uint4* __restrict__ tx1,
        const uint4* __restrict__ tx2, const uint4* __restrict__ tx3,
        const uint4* __restrict__ bfrag,
        const float* __restrict__ cheb_b, const float* __restrict__ fw,
        const float* __restrict__ fb, float* __restrict__ out, int n) {
    int tid = threadIdx.x;
    int lane = tid & 63;
    int wave = tid >> 6;
    int q = lane >> 4, m = lane & 15;
    int node_base = blockIdx.x * 64 + wave * 16;
    int node = node_base + m;
    size_t nd = (node < n) ? (size_t)node : 0;   // clamp; store is guarded

    f32x4 acc[8];
#pragma unroll
    for (int t = 0; t < 8; ++t) acc[t] = (f32x4){0.f, 0.f, 0.f, 0.f};

    const uint4* txs[4] = {tx0, tx1, tx2, tx3};
#pragma unroll
    for (int kk = 0; kk < 8; ++kk) {
        U16 av;
        av.u = txs[kk >> 1][nd * 8 + (kk & 1) * 4 + q];
#pragma unroll
        for (int ht = 0; ht < 8; ++ht) {
            U16 bv;
            bv.u = bfrag[(kk * 8 + ht) * 64 + lane];
            acc[ht] = __builtin_amdgcn_mfma_f32_16x16x32_f16(av.h8, bv.h8, acc[ht], 0, 0, 0);
        }
    }

    float s[4] = {0.f, 0.f, 0.f, 0.f};
#pragma unroll
    for (int ht = 0; ht < 8; ++ht) {
        int h = ht * 16 + m;
        float cb = cheb_b[h];
        float fv = fw[h];
#pragma unroll
        for (int r = 0; r < 4; ++r)
            s[r] = fmaf(tanh_fast(acc[ht][r] + cb), fv, s[r]);
    }
#pragma unroll
    for (int r = 0; r < 4; ++r) {
        for (int msk = 1; msk < 16; msk <<= 1)
            s[r] += __shfl_xor(s[r], msk, 64);
    }
    if (m == 0) {
        float fb0 = fb[0];
#pragma unroll
        for (int r = 0; r < 4; ++r) {
            int o = node_base + q * 4 + r;
            if (o < n) out[o] = s[r] + fb0;
        }
    }
}

extern "C" void kernel_launch(void* const* d_in, const int* in_sizes, int n_in,
                              void* d_out, int out_size, void* d_ws, size_t ws_size,
                              hipStream_t stream) {
    const float* features = (const float*)d_in[0];
    const int*   edge_index = (const int*)d_in[1];
    const float* cheb_w  = (const float*)d_in[2];
    const float* cheb_b  = (const float*)d_in[3];
    const float* final_w = (const float*)d_in[4];
    const float* final_b = (const float*)d_in[5];
    int N = in_sizes[0] / FIN;
    int E = in_sizes[1] / 2;
    const int* row = edge_index;        // edge_index[0, :]
    const int* col = edge_index + E;    // edge_index[1, :]
    int E_pad = E + 4 * N;              // allocation bound on padded edges
    int stride8 = (N + 7) / 8;
    int nblk = (N + 255) / 256;

    char* p = (char*)d_ws;
    auto alloc = [&](size_t bytes) {
        char* r = p;
        p += (bytes + 255) & ~(size_t)255;
        return r;
    };
    // ctr + deg + epk adjacent: ONE memset zeroes all (epk pads = col0,w0).
    int*   ctr     = (int*)alloc(256);
    int*   deg     = (int*)alloc((size_t)N * 4);
    int2*  epk     = (int2*)alloc((size_t)E_pad * 8);
    size_t zero_bytes = (char*)(epk + E_pad) - (char*)ctr;
    float* dinv    = (float*)alloc((size_t)N * 4);
    int2*  rowspan = (int2*)alloc((size_t)N * 8);
    int*   cursor  = (int*)alloc((size_t)(stride8 * 8) * 4);
    int*   blockBin= (int*)alloc((size_t)32 * nblk * 4);  // bin-major
    int*   binBase = (int*)alloc(32 * 4);
    int*   rowlist = (int*)alloc((size_t)N * 4);
    uint4* feath   = (uint4*)alloc((size_t)N * FIN * 2);  // fp16 rows
    uint4* tx1h    = (uint4*)alloc((size_t)N * FIN * 2);
    uint4* tx2h    = (uint4*)alloc((size_t)N * FIN * 2);
    uint4* tx3h    = (uint4*)alloc((size_t)N * FIN * 2);
    uint4* bfrag   = (uint4*)alloc(4096 * 16);            // 64 KB B fragments

    hipMemsetAsync(ctr, 0, zero_bytes, stream);
    int n8 = N * FIN / 8;
    int eb = (E + 255) / 256;
    fused_pre<<<eb, 256, 0, stream>>>(row, deg, E, (const float4*)features, feath,
                                      n8, cheb_w, bfrag);
    alloc_rows<<<nblk, 256, 0, stream>>>(deg, dinv, rowspan, cursor, ctr,
                                         blockBin, nblk, N, stride8);
    bin_scan2<<<1, 256, 0, stream>>>(blockBin, binBase, nblk);
    sort_rows<<<nblk, 256, 0, stream>>>(deg, blockBin, binBase, rowlist, nblk, N);
    scatter_xcd<<<eb * 8, 256, 0, stream>>>(row, col, dinv, cursor, epk, E, stride8);

    int spmm_blocks = (((N + 7) / 8) * 64 + 255) / 256;
    // Tx1 = L_hat @ x
    spmm_h<<<spmm_blocks, 256, 0, stream>>>(rowlist, rowspan, epk, feath, nullptr,
                                            1.f, tx1h, N);
    // Tx2 = 2 * L_hat @ Tx1 - Tx0
    spmm_h<<<spmm_blocks, 256, 0, stream>>>(rowlist, rowspan, epk, tx1h, feath,
                                            2.f, tx2h, N);
    // Tx3 = 2 * L_hat @ Tx2 - Tx1
    spmm_h<<<spmm_blocks, 256, 0, stream>>>(rowlist, rowspan, epk, tx2h, tx1h,
                                            2.f, tx3h, N);

    gemm_mfma<<<(N + 63) / 64, 256, 0, stream>>>(feath, tx1h, tx2h, tx3h, bfrag,
                                                 cheb_b, final_w, final_b,
                                                 (float*)d_out, N);
}

// Round 16
// 216.731 us; speedup vs baseline: 1.4508x; 1.0999x over previous
//
#include <hip/hip_runtime.h>
#include <hip/hip_fp16.h>
#include <math.h>

// ChebConv (K=4) GNN head. N=50000, E=800000, F_IN=64, H=128.
// R16 = revert to R12 (best measured: 217us). R13 (NT hints), R14/R15
// (degree-bucketed SPMM) all regressed vs this configuration.
// Structure: fused_pre (deg count + fp16 cvt + B-fragment swizzle),
// atomic row-span allocation (no scan chain), XCD-owned scatter with
// permuted cursors, 2-deep pipelined gather SPMM x3, LDS-free MFMA GEMM.

#define FIN 64
#define HDIM 128

typedef _Float16 half8 __attribute__((ext_vector_type(8)));
typedef float f32x4 __attribute__((ext_vector_type(4)));

union U16 { uint4 u; __half2 h2[4]; half8 h8; };

// count_deg + cvt_feat + make_bfrag fused (mutually independent; grid sized
// for E covers all with guards).
__global__ void fused_pre(const int* __restrict__ row, int* __restrict__ deg, int E,
                          const float4* __restrict__ fsrc, uint4* __restrict__ fdst, int n8,
                          const float* __restrict__ W, uint4* __restrict__ bfrag) {
    int i = blockIdx.x * blockDim.x + threadIdx.x;
    if (i < E) atomicAdd(&deg[row[i]], 1);
    if (i < n8) {
        float4 a = fsrc[i * 2], b = fsrc[i * 2 + 1];
        U16 v;
        v.h2[0] = __float22half2_rn(make_float2(a.x, a.y));
        v.h2[1] = __float22half2_rn(make_float2(a.z, a.w));
        v.h2[2] = __float22half2_rn(make_float2(b.x, b.y));
        v.h2[3] = __float22half2_rn(make_float2(b.z, b.w));
        fdst[i] = v.u;
    }
    if (i < 8 * 8 * 64) {
        int lane = i & 63;
        int ht = (i >> 6) & 7;
        int kk = i >> 9;
        int h = ht * 16 + (lane & 15);
        int kb = kk * 32 + (lane >> 4) * 8;
        U16 v;
#pragma unroll
        for (int j = 0; j < 4; ++j) {
            float a = W[(kb + 2 * j) * HDIM + h];
            float b = W[(kb + 2 * j + 1) * HDIM + h];
            v.h2[j] = __float22half2_rn(make_float2(a, b));
        }
        bfrag[i] = v.u;
    }
}

// Row-span allocation: wave shfl-scan of padded degrees, one atomicAdd per
// wave on a global counter. Spans are contiguous per row but NOT row-ordered
// (irrelevant for correctness). Also computes dinv and permuted cursors.
__global__ void alloc_rows(const int* __restrict__ deg, float* __restrict__ dinv,
                           int2* __restrict__ rowspan, int* __restrict__ cursor,
                           int* __restrict__ ctr, int n, int stride8) {
    int i = blockIdx.x * blockDim.x + threadIdx.x;
    int lane = threadIdx.x & 63;
    int d = (i < n) ? deg[i] : 0;
    if (i < n) dinv[i] = (d > 0) ? rsqrtf((float)d) : 0.f;
    int pd = (i < n) ? ((d + 3) & ~3) : 0;
    int x = pd;                        // inclusive wave scan
    for (int off = 1; off < 64; off <<= 1) {
        int t = __shfl_up(x, off, 64);
        if (lane >= off) x += t;
    }
    int excl = x - pd;
    int total = __shfl(x, 63, 64);
    int base = 0;
    if (lane == 0 && total > 0) base = atomicAdd(ctr, total);
    base = __shfl(base, 0, 64);
    if (i < n) {
        int b = base + excl;
        rowspan[i] = make_int2(b, b + pd);
        cursor[(i & 7) * stride8 + (i >> 3)] = b;
    }
}

// XCD-owned scatter: grid = 8 * ceil(E/256); consecutive blockIdx round-robin
// across XCDs, so xcd = blockIdx&7, e-chunk = blockIdx>>3. Each block filters
// edges whose row%8 == xcd -> every epk line + cursor written by ONE XCD.
// (R13's single-pass variant measured 46us; this stays under the 44us floor.)
__global__ void scatter_xcd(const int* __restrict__ row, const int* __restrict__ col,
                            const float* __restrict__ dinv, int* __restrict__ cursor,
                            int2* __restrict__ epk, int E, int stride8) {
    int xcd = blockIdx.x & 7;
    int e = (blockIdx.x >> 3) * blockDim.x + threadIdx.x;
    if (e < E) {
        int r = row[e];
        if ((r & 7) == xcd) {
            int c = col[e];
            int p = atomicAdd(&cursor[xcd * stride8 + (r >> 3)], 1);
            float w = -dinv[r] * dinv[c];   // L_hat = -D^-1/2 A D^-1/2
            epk[p] = make_int2(c, __float_as_int(w));
        }
    }
}

// 8 rows/wave, 8 lanes/row, 16B (8 halfs) per lane, fp32 accumulate.
// Padded spans: (e-s)%4 == 0, pad slots (col=0,w=0). 2-deep pipeline:
// descriptors prefetched 2 iters ahead, gathers issued 1 iter ahead.
// Bound: per-CU L1-miss concurrency on the 6.4MB random-gather table
// (~110MB L1-miss traffic/dispatch); sorting/NT/XCD-split all measured worse.
__global__ __launch_bounds__(256) void spmm_h(
        const int2* __restrict__ rowspan, const int2* __restrict__ epk,
        const uint4* __restrict__ in8, const uint4* __restrict__ prev8,
        float scale, uint4* __restrict__ out8, int n) {
    int lane = threadIdx.x & 63;
    int wid = (blockIdx.x * blockDim.x + threadIdx.x) >> 6;
    int li = lane & 7, g = lane >> 3;
    int r = wid * 8 + g;
    if (r >= n) return;
    int2 span = rowspan[r];
    int s = span.x, e = span.y;

    U16 pv;
    if (prev8) pv.u = prev8[(size_t)r * 8 + li];   // in flight across the loop

    float acc[8];
#pragma unroll
    for (int j = 0; j < 8; ++j) acc[j] = 0.f;

    if (s < e) {
        int2 mc[4], mn[4];
        U16 vc[4];
#pragma unroll
        for (int j = 0; j < 4; ++j) mc[j] = epk[s + j];        // iter0 desc
#pragma unroll
        for (int j = 0; j < 4; ++j) vc[j].u = in8[(size_t)mc[j].x * 8 + li];
        if (s + 4 < e) {
#pragma unroll
            for (int j = 0; j < 4; ++j) mn[j] = epk[s + 4 + j]; // iter1 desc
        }
        for (int p = s;;) {
            bool more = p + 4 < e;
            bool more2 = p + 8 < e;
            U16 vn[4];
            int2 m2[4];
            if (more) {                                         // iter i+1 gathers
#pragma unroll
                for (int j = 0; j < 4; ++j) vn[j].u = in8[(size_t)mn[j].x * 8 + li];
            }
            if (more2) {                                        // iter i+2 desc
#pragma unroll
                for (int j = 0; j < 4; ++j) m2[j] = epk[p + 8 + j];
            }
            float w0 = __int_as_float(mc[0].y), w1 = __int_as_float(mc[1].y);
            float w2 = __int_as_float(mc[2].y), w3 = __int_as_float(mc[3].y);
#pragma unroll
            for (int j = 0; j < 4; ++j) {
                float2 f0 = __half22float2(vc[0].h2[j]);
                float2 f1 = __half22float2(vc[1].h2[j]);
                float2 f2 = __half22float2(vc[2].h2[j]);
                float2 f3 = __half22float2(vc[3].h2[j]);
                acc[2 * j]     = fmaf(w0, f0.x, acc[2 * j]);
                acc[2 * j + 1] = fmaf(w0, f0.y, acc[2 * j + 1]);
                acc[2 * j]     = fmaf(w1, f1.x, acc[2 * j]);
                acc[2 * j + 1] = fmaf(w1, f1.y, acc[2 * j + 1]);
                acc[2 * j]     = fmaf(w2, f2.x, acc[2 * j]);
                acc[2 * j + 1] = fmaf(w2, f2.y, acc[2 * j + 1]);
                acc[2 * j]     = fmaf(w3, f3.x, acc[2 * j]);
                acc[2 * j + 1] = fmaf(w3, f3.y, acc[2 * j + 1]);
            }
            if (!more) break;
#pragma unroll
            for (int j = 0; j < 4; ++j) {
                mc[j] = mn[j];
                mn[j] = m2[j];   // garbage when !more2; never gathered then
                vc[j] = vn[j];
            }
            p += 4;
        }
    }

    float res[8];
    if (prev8) {
#pragma unroll
        for (int t = 0; t < 4; ++t) {
            float2 f = __half22float2(pv.h2[t]);
            res[2 * t]     = fmaf(scale, acc[2 * t], -f.x);
            res[2 * t + 1] = fmaf(scale, acc[2 * t + 1], -f.y);
        }
    } else {
#pragma unroll
        for (int j = 0; j < 8; ++j) res[j] = scale * acc[j];
    }
    U16 ru;
#pragma unroll
    for (int t = 0; t < 4; ++t)
        ru.h2[t] = __float22half2_rn(make_float2(res[2 * t], res[2 * t + 1]));
    out8[(size_t)r * 8 + li] = ru.u;
}

__device__ inline float tanh_fast(float x) {
    x = fmaxf(-10.f, fminf(10.f, x));
    float e = __expf(2.f * x);
    return (e - 1.f) / (e + 1.f);
}

// MFMA GEMM + tanh + final dot. Block = 256 thr = 4 waves; wave = 16 nodes x
// 128 h (8 tiles of 16x16, K=32/step, 8 steps over K=256). LDS-free:
// A frag = one 16B global load; B frags pre-swizzled (64KB, L2-resident).
// C layout: col(h)=lane&15, row=q*4+reg.
__global__ __launch_bounds__(256) void gemm_mfma(
        const uint4* __restrict__ tx0, const uint4* __restrict__ tx1,
        const uint4* __restrict__ tx2, const uint4* __restrict__ tx3,
        const uint4* __restrict__ bfrag,
        const float* __restrict__ cheb_b, const float* __restrict__ fw,
        const float* __restrict__ fb, float* __restrict__ out, int n) {
    int tid = threadIdx.x;
    int lane = tid & 63;
    int wave = tid >> 6;
    int q = lane >> 4, m = lane & 15;
    int node_base = blockIdx.x * 64 + wave * 16;
    int node = node_base + m;
    size_t nd = (node < n) ? (size_t)node : 0;   // clamp; store is guarded

    f32x4 acc[8];
#pragma unroll
    for (int t = 0; t < 8; ++t) acc[t] = (f32x4){0.f, 0.f, 0.f, 0.f};

    const uint4* txs[4] = {tx0, tx1, tx2, tx3};
#pragma unroll
    for (int kk = 0; kk < 8; ++kk) {
        U16 av;
        av.u = txs[kk >> 1][nd * 8 + (kk & 1) * 4 + q];
#pragma unroll
        for (int ht = 0; ht < 8; ++ht) {
            U16 bv;
            bv.u = bfrag[(kk * 8 + ht) * 64 + lane];
            acc[ht] = __builtin_amdgcn_mfma_f32_16x16x32_f16(av.h8, bv.h8, acc[ht], 0, 0, 0);
        }
    }

    float s[4] = {0.f, 0.f, 0.f, 0.f};
#pragma unroll
    for (int ht = 0; ht < 8; ++ht) {
        int h = ht * 16 + m;
        float cb = cheb_b[h];
        float fv = fw[h];
#pragma unroll
        for (int r = 0; r < 4; ++r)
            s[r] = fmaf(tanh_fast(acc[ht][r] + cb), fv, s[r]);
    }
#pragma unroll
    for (int r = 0; r < 4; ++r) {
        for (int msk = 1; msk < 16; msk <<= 1)
            s[r] += __shfl_xor(s[r], msk, 64);
    }
    if (m == 0) {
        float fb0 = fb[0];
#pragma unroll
        for (int r = 0; r < 4; ++r) {
            int o = node_base + q * 4 + r;
            if (o < n) out[o] = s[r] + fb0;
        }
    }
}

extern "C" void kernel_launch(void* const* d_in, const int* in_sizes, int n_in,
                              void* d_out, int out_size, void* d_ws, size_t ws_size,
                              hipStream_t stream) {
    const float* features = (const float*)d_in[0];
    const int*   edge_index = (const int*)d_in[1];
    const float* cheb_w  = (const float*)d_in[2];
    const float* cheb_b  = (const float*)d_in[3];
    const float* final_w = (const float*)d_in[4];
    const float* final_b = (const float*)d_in[5];
    int N = in_sizes[0] / FIN;
    int E = in_sizes[1] / 2;
    const int* row = edge_index;        // edge_index[0, :]
    const int* col = edge_index + E;    // edge_index[1, :]
    int E_pad = E + 4 * N;              // allocation bound on padded edges
    int stride8 = (N + 7) / 8;

    char* p = (char*)d_ws;
    auto alloc = [&](size_t bytes) {
        char* r = p;
        p += (bytes + 255) & ~(size_t)255;
        return r;
    };
    // ctr + deg + epk adjacent: ONE memset zeroes counter, degrees, and epk
    // (pad slots = col 0, w 0).
    int*   ctr    = (int*)alloc(256);
    int*   deg    = (int*)alloc((size_t)N * 4);
    int2*  epk    = (int2*)alloc((size_t)E_pad * 8);
    size_t zero_bytes = (char*)(epk + E_pad) - (char*)ctr;
    float* dinv   = (float*)alloc((size_t)N * 4);
    int2*  rowspan= (int2*)alloc((size_t)N * 8);
    int*   cursor = (int*)alloc((size_t)(stride8 * 8) * 4);
    uint4* feath  = (uint4*)alloc((size_t)N * FIN * 2);   // fp16 rows
    uint4* tx1h   = (uint4*)alloc((size_t)N * FIN * 2);
    uint4* tx2h   = (uint4*)alloc((size_t)N * FIN * 2);
    uint4* tx3h   = (uint4*)alloc((size_t)N * FIN * 2);
    uint4* bfrag  = (uint4*)alloc(4096 * 16);             // 64 KB B fragments

    hipMemsetAsync(ctr, 0, zero_bytes, stream);
    int n8 = N * FIN / 8;
    int eb = (E + 255) / 256;
    fused_pre<<<eb, 256, 0, stream>>>(row, deg, E, (const float4*)features, feath,
                                      n8, cheb_w, bfrag);
    alloc_rows<<<(N + 255) / 256, 256, 0, stream>>>(deg, dinv, rowspan, cursor,
                                                    ctr, N, stride8);
    scatter_xcd<<<eb * 8, 256, 0, stream>>>(row, col, dinv, cursor, epk, E, stride8);

    int spmm_blocks = (((N + 7) / 8) * 64 + 255) / 256;
    // Tx1 = L_hat @ x
    spmm_h<<<spmm_blocks, 256, 0, stream>>>(rowspan, epk, feath, nullptr, 1.f, tx1h, N);
    // Tx2 = 2 * L_hat @ Tx1 - Tx0
    spmm_h<<<spmm_blocks, 256, 0, stream>>>(rowspan, epk, tx1h, feath, 2.f, tx2h, N);
    // Tx3 = 2 * L_hat @ Tx2 - Tx1
    spmm_h<<<spmm_blocks, 256, 0, stream>>>(rowspan, epk, tx2h, tx1h, 2.f, tx3h, N);

    gemm_mfma<<<(N + 63) / 64, 256, 0, stream>>>(feath, tx1h, tx2h, tx3h, bfrag,
                                                 cheb_b, final_w, final_b,
                                                 (float*)d_out, N);
}